// Round 5
// baseline (140.960 us; speedup 1.0000x reference)
//
#include <hip/hip_runtime.h>
#include <hip/hip_bf16.h>

// Problem constants
#define L_DIM 128
#define N_DIM 32
#define C_DIM 128
#define K_DIM 128   // DIM_MLP
#define OUT_DIM 128

typedef __attribute__((ext_vector_type(8))) short short8;
typedef __attribute__((ext_vector_type(4))) float float4v;

static __device__ __forceinline__ short bf16_bits(float f) {
    __bf16 h = (__bf16)f;   // RNE
    return __builtin_bit_cast(short, h);
}
static __device__ __forceinline__ float bf16_to_f32(short s) {
    return __builtin_bit_cast(float, ((unsigned)(unsigned short)s) << 16);
}

// ---------------------------------------------------------------------------
// Kernel 1: precompute.
//   blocks 0..255 : 16 flat rows each, weights staged tile-wise via LDS.
//     Pb = bf16(x·W1a) ; Q = x·W1b + b1 ; V = relu(x·Vw1+vb1)·Vw2 + vb2
//   blocks 256..319: W2s = attn_w2 swizzled into bf16 MFMA B-fragment order
// ---------------------------------------------------------------------------
__global__ __launch_bounds__(256) void k_pre(
    const float* __restrict__ x,
    const float* __restrict__ attn_w1, const float* __restrict__ attn_b1,
    const float* __restrict__ attn_w2,
    const float* __restrict__ value_w1, const float* __restrict__ value_b1,
    const float* __restrict__ value_w2, const float* __restrict__ value_b2,
    unsigned short* __restrict__ Pb, float* __restrict__ Q,
    float* __restrict__ V, short* __restrict__ W2s)
{
    int bid = blockIdx.x;
    int tid = threadIdx.x;
    if (bid >= 256) {
        // W2 swizzle: element e = ((((ct*4+mi)*4+quad)*16+col)*8+idx)
        int e = (bid - 256) * 256 + tid;              // 64*256 = 16384 elems
        int idx  = e & 7;
        int colr = (e >> 3) & 15;
        int quad = (e >> 7) & 3;
        int mi   = (e >> 9) & 3;
        int ct   = e >> 11;
        int k = quad * 8 + 32 * mi + idx;
        int c = ct * 16 + colr;
        W2s[e] = bf16_bits(attn_w2[k * OUT_DIM + c]);
        return;
    }

    __shared__ float xs[16][C_DIM];          // 8 KB
    __shared__ float W_lds[3][32][K_DIM];    // 48 KB (weight tiles)
    __shared__ float hvs[16][K_DIM];         // 8 KB

    int r0 = bid * 16;                       // first flat row (i*N+b)

    #pragma unroll
    for (int t = 0; t < 2; ++t) {
        int e4 = t * 256 + tid;
        int row = e4 >> 5, c4 = (e4 & 31) * 4;
        *(float4v*)&xs[row][c4] = *(const float4v*)(x + (r0 + row) * C_DIM + c4);
    }

    int ks   = tid & 127;      // output column k (or c)
    int half = tid >> 7;       // rows 0-7 vs 8-15

    float pa[8] = {0,0,0,0,0,0,0,0};
    float qa[8] = {0,0,0,0,0,0,0,0};
    float ha[8] = {0,0,0,0,0,0,0,0};

    for (int ct4 = 0; ct4 < 4; ++ct4) {
        #pragma unroll
        for (int t = 0; t < 4; ++t) {
            int e4 = t * 256 + tid;                   // 1024 float4 / matrix
            int cc = e4 >> 5, k4 = (e4 & 31) * 4;
            *(float4v*)&W_lds[0][cc][k4] =
                *(const float4v*)(attn_w1 + (ct4 * 32 + cc) * K_DIM + k4);
            *(float4v*)&W_lds[1][cc][k4] =
                *(const float4v*)(attn_w1 + (C_DIM + ct4 * 32 + cc) * K_DIM + k4);
            *(float4v*)&W_lds[2][cc][k4] =
                *(const float4v*)(value_w1 + (ct4 * 32 + cc) * K_DIM + k4);
        }
        __syncthreads();

        for (int g = 0; g < 8; ++g) {                 // 4-c groups
            float4v xr4[8];
            #pragma unroll
            for (int r = 0; r < 8; ++r)
                xr4[r] = *(const float4v*)&xs[half * 8 + r][ct4 * 32 + g * 4];
            #pragma unroll
            for (int u = 0; u < 4; ++u) {
                int cc = g * 4 + u;
                float wa = W_lds[0][cc][ks];
                float wb = W_lds[1][cc][ks];
                float wv = W_lds[2][cc][ks];
                #pragma unroll
                for (int r = 0; r < 8; ++r) {
                    float xr = xr4[r][u];
                    pa[r] = fmaf(xr, wa, pa[r]);
                    qa[r] = fmaf(xr, wb, qa[r]);
                    ha[r] = fmaf(xr, wv, ha[r]);
                }
            }
        }
        __syncthreads();
    }

    float b1 = attn_b1[ks], vb1 = value_b1[ks];
    #pragma unroll
    for (int r = 0; r < 8; ++r) {
        int rr = r0 + half * 8 + r;
        int i = rr >> 5, b = rr & 31;                  // rr = i*N + b
        Pb[(b * L_DIM + i) * K_DIM + ks] = (unsigned short)bf16_bits(pa[r]);
        Q[(b * L_DIM + i) * K_DIM + ks] = qa[r] + b1;
        hvs[half * 8 + r][ks] = fmaxf(ha[r] + vb1, 0.f);
    }

    float va[8] = {0,0,0,0,0,0,0,0};
    for (int kt = 0; kt < 4; ++kt) {
        #pragma unroll
        for (int t = 0; t < 4; ++t) {
            int e4 = t * 256 + tid;
            int cc = e4 >> 5, k4 = (e4 & 31) * 4;
            *(float4v*)&W_lds[0][cc][k4] =
                *(const float4v*)(value_w2 + (kt * 32 + cc) * OUT_DIM + k4);
        }
        __syncthreads();
        for (int g = 0; g < 8; ++g) {
            float4v hv4[8];
            #pragma unroll
            for (int r = 0; r < 8; ++r)
                hv4[r] = *(const float4v*)&hvs[half * 8 + r][kt * 32 + g * 4];
            #pragma unroll
            for (int u = 0; u < 4; ++u) {
                float w = W_lds[0][g * 4 + u][ks];
                #pragma unroll
                for (int r = 0; r < 8; ++r)
                    va[r] = fmaf(hv4[r][u], w, va[r]);
            }
        }
        __syncthreads();
    }
    float vb2 = value_b2[ks];
    #pragma unroll
    for (int r = 0; r < 8; ++r) {
        int rr = r0 + half * 8 + r;
        int i = rr >> 5, b = rr & 31;
        V[(b * L_DIM + i) * OUT_DIM + ks] = va[r] + vb2;
    }
}

// ---------------------------------------------------------------------------
// Kernel 2: fused pairwise-MLP + j-reduce.
//   grid 1024 blocks x 512 threads; b = blk&31 (XCD-local), itile = blk>>5.
//   8 waves = ipair(2 i's) x cquad(2 c-tiles). Everything register-resident
//   within a 128-VGPR budget: bfrag[2][4]=32, P bf16 pb[2][4]=32.
//   Per round (16 j's): Q tile from dbuf LDS; per k-slice build A-frag
//   (relu(P+Q) -> bf16) and chain MFMAs into c4; V-scale (8 scalars, L2-hot);
//   one barrier/round. End: fold b2*Sv, quad shuffle reduce, write.
// ---------------------------------------------------------------------------
#define QSTR 132   // 128 + 4-float pad -> uniform bank spread

__global__ __launch_bounds__(512) void k_main(
    const unsigned short* __restrict__ Pb, const float* __restrict__ Q,
    const float* __restrict__ V, const short* __restrict__ W2s,
    const float* __restrict__ attn_b2, float* __restrict__ out)
{
    __shared__ float Qb[2][16 * QSTR];       // 16.9 KB double-buffered Q tile

    int blk   = blockIdx.x;
    int b     = blk & 31;                    // XCD-local: per XCD only 4 b's
    int itile = blk >> 5;
    int tid   = threadIdx.x;
    int wave  = tid >> 6;
    int lane  = tid & 63;
    int quad  = lane >> 4;
    int col   = lane & 15;
    int ipair = wave & 1;
    int cquad = wave >> 1;
    int i0    = itile * 4 + ipair * 2;
    int ct0   = cquad * 2;

    // resident B-frags: 2 c-tiles x 4 k-slices (32 VGPR)
    short8 bfrag[2][4];
    const short8* w2p = (const short8*)W2s;
    #pragma unroll
    for (int c2 = 0; c2 < 2; ++c2)
        #pragma unroll
        for (int mi = 0; mi < 4; ++mi)
            bfrag[c2][mi] = w2p[(((ct0 + c2) * 4 + mi) * 4 + quad) * 16 + col];

    // resident P (bf16) for this wave's 2 i's (32 VGPR)
    short8 pb[2][4];
    #pragma unroll
    for (int il = 0; il < 2; ++il) {
        const unsigned short* pr = Pb + (size_t)(b * L_DIM + i0 + il) * K_DIM;
        #pragma unroll
        for (int mi = 0; mi < 4; ++mi)
            pb[il][mi] = *(const short8*)(pr + quad * 8 + mi * 32);
    }

    // Q staging: 512 threads, 1 float4 each = full 16x128 tile
    int srow = tid >> 5;             // 0..15
    int sc4  = (tid & 31) * 4;
    const float* Qbase = Q + (size_t)b * L_DIM * K_DIM;
    const float* Vbase = V + (size_t)b * L_DIM * OUT_DIM;

    *(float4v*)&Qb[0][srow * QSTR + sc4] =
        *(const float4v*)(Qbase + srow * K_DIM + sc4);
    __syncthreads();

    float acc[2][2] = {};
    float sv[2]     = {};

    for (int r = 0; r < 8; ++r) {
        int cur = r & 1;

        // next Q tile -> regs (overlaps compute)
        float4v nq;
        if (r < 7)
            nq = *(const float4v*)(Qbase + ((r + 1) * 16 + srow) * K_DIM + sc4);

        // V prefetch: 8 scalars (disjoint across cquad waves, L2-hot)
        const float* Vr = Vbase + (r * 16 + quad * 4) * OUT_DIM;
        float vv[2][4];
        #pragma unroll
        for (int c2 = 0; c2 < 2; ++c2)
            #pragma unroll
            for (int rr = 0; rr < 4; ++rr)
                vv[c2][rr] = Vr[rr * OUT_DIM + (ct0 + c2) * 16 + col];

        float4v c4[2][2] = {};
        #pragma unroll
        for (int mi = 0; mi < 4; ++mi) {
            const float* qc = &Qb[cur][col * QSTR + quad * 8 + mi * 32];
            float4v q0 = *(const float4v*)qc;
            float4v q1 = *(const float4v*)(qc + 4);
            #pragma unroll
            for (int il = 0; il < 2; ++il) {
                float4v p0, p1;
                #pragma unroll
                for (int t = 0; t < 4; ++t) {
                    p0[t] = bf16_to_f32(pb[il][mi][t]);
                    p1[t] = bf16_to_f32(pb[il][mi][t + 4]);
                }
                float4v h0 = __builtin_elementwise_max(p0 + q0, (float4v)0.f);
                float4v h1 = __builtin_elementwise_max(p1 + q1, (float4v)0.f);
                short8 a;
                #pragma unroll
                for (int t = 0; t < 4; ++t) {
                    a[t]     = bf16_bits(h0[t]);
                    a[t + 4] = bf16_bits(h1[t]);
                }
                #pragma unroll
                for (int c2 = 0; c2 < 2; ++c2)
                    c4[il][c2] = __builtin_amdgcn_mfma_f32_16x16x32_bf16(
                        a, bfrag[c2][mi], c4[il][c2], 0, 0, 0);
            }
        }

        // V-scaled accumulate + Sv partials (all linear in quad partials)
        #pragma unroll
        for (int c2 = 0; c2 < 2; ++c2)
            #pragma unroll
            for (int rr = 0; rr < 4; ++rr) {
                float v = vv[c2][rr];
                acc[0][c2] = fmaf(c4[0][c2][rr], v, acc[0][c2]);
                acc[1][c2] = fmaf(c4[1][c2][rr], v, acc[1][c2]);
                sv[c2] += v;
            }

        if (r < 7)
            *(float4v*)&Qb[cur ^ 1][srow * QSTR + sc4] = nq;
        __syncthreads();
    }

    #pragma unroll
    for (int il = 0; il < 2; ++il)
        #pragma unroll
        for (int c2 = 0; c2 < 2; ++c2) {
            int cc = (ct0 + c2) * 16 + col;
            float tot = fmaf(attn_b2[cc], sv[c2], acc[il][c2]);
            tot += __shfl_xor(tot, 16, 64);
            tot += __shfl_xor(tot, 32, 64);
            if (quad == 0)
                out[((i0 + il) * N_DIM + b) * OUT_DIM + cc] = tot;
        }
}

// ---------------------------------------------------------------------------
extern "C" void kernel_launch(void* const* d_in, const int* in_sizes, int n_in,
                              void* d_out, int out_size, void* d_ws, size_t ws_size,
                              hipStream_t stream)
{
    const float* x        = (const float*)d_in[0];
    const float* attn_w1  = (const float*)d_in[1];
    const float* attn_b1  = (const float*)d_in[2];
    const float* attn_w2  = (const float*)d_in[3];
    const float* attn_b2  = (const float*)d_in[4];
    const float* value_w1 = (const float*)d_in[5];
    const float* value_b1 = (const float*)d_in[6];
    const float* value_w2 = (const float*)d_in[7];
    const float* value_b2 = (const float*)d_in[8];
    float* out = (float*)d_out;

    // Workspace (floats): Q 512K | V 512K | Pb(bf16) 256K | W2s(bf16) 8K
    float* ws = (float*)d_ws;
    float* Q  = ws;
    float* V  = ws + 524288;
    unsigned short* Pbuf = (unsigned short*)(ws + 1048576);
    short* W2s = (short*)(ws + 1310720);

    k_pre<<<320, 256, 0, stream>>>(x, attn_w1, attn_b1, attn_w2,
                                   value_w1, value_b1, value_w2, value_b2,
                                   Pbuf, Q, V, W2s);
    k_main<<<1024, 512, 0, stream>>>(Pbuf, Q, V, W2s, attn_b2, out);
}